// Round 14
// baseline (216.124 us; speedup 1.0000x reference)
//
#include <hip/hip_runtime.h>
#include <hip/hip_bf16.h>

#define BS 32
#define LQ 300
#define CDIM 256
#define HEADS 8
#define HD 32
#define NLEVELS 3
#define NPOINTS 4
#define LV 8400   // 80*80 + 40*40 + 20*20
#define NOA 288   // 192 offset cols + 96 att cols

typedef __attribute__((ext_vector_type(4))) float f32x4;
typedef __attribute__((ext_vector_type(8))) short short8;
typedef __attribute__((ext_vector_type(8))) unsigned short u16x8;
typedef __attribute__((ext_vector_type(4))) unsigned short u16x4;

__device__ __forceinline__ unsigned short f2bf(float f) {
    __hip_bfloat16 h = __float2bfloat16(f);
    return __bfloat16_as_ushort(h);
}
__device__ __forceinline__ float bf2f(unsigned short u) {
    union { unsigned u; float f; } v; v.u = ((unsigned)u) << 16;
    return v.f;
}

// ---------------------------------------------------------------------------
// Prep (fused): WvT, WoutT (256 cols each), WoaT (288 cols).  grid = 800.
// ---------------------------------------------------------------------------
__global__ void prep_weights_kernel(
    const float* __restrict__ Wv, const float* __restrict__ Wout,
    const float* __restrict__ Woff, const float* __restrict__ Watt,
    unsigned short* __restrict__ WvT, unsigned short* __restrict__ WoutT,
    unsigned short* __restrict__ WoaT)
{
    const int bid = blockIdx.x;
    const int k = threadIdx.x;
    if (bid < 256) {
        WvT[bid * 256 + k] = f2bf(Wv[k * 256 + bid]);
    } else if (bid < 512) {
        const int n = bid - 256;
        WoutT[n * 256 + k] = f2bf(Wout[k * 256 + n]);
    } else {
        const int n = bid - 512;
        const float w = (n < 192) ? Woff[k * 192 + n] : Watt[k * 96 + (n - 192)];
        WoaT[n * 256 + k] = f2bf(w);
    }
}

#define BM 128
#define BK 32
#define PAD 40     // bf16 elems per LDS row (80 B stride)
#define EP2 136    // proj epilogue row stride (272 B = 17*16, 16B-aligned)
#define NT (CDIM / BK)

// ---------------------------------------------------------------------------
// Kernel A: v = bf16( value @ Wv + bv ), swapped roles:
// D[n][m] = WvT(n,k) x value^T(k,m).
// EXACT m97 geometry: 128x128 output tile (N tiled in 2), 256 thr = 4 waves
// (2n x 2m), wave tile 64x64, acc[4][4].  Per-K-step staging = 8 KB W half +
// 8 KB X; double-buffered LDS = 40 KB -> 4 blocks/CU (4 independent barrier
// groups overlap each other's vmcnt(0)+s_barrier drains — m97's mechanism,
// never realized in the BN=256 variants which fit only 2 blocks/CU).
// Grid 2100x2 = 4200 with XCD-chunked bijective swizzle: the 2 n-tiles of
// one m-tile are consecutive on the SAME XCD -> X re-read is L2-local.
// Plain __syncthreads (proven m97 loop).  Epilogue via LDS, coalesced.
// ---------------------------------------------------------------------------
__global__ __launch_bounds__(256) void proj_value_mfma(
    const float* __restrict__ value, const unsigned short* __restrict__ WvT,
    const float* __restrict__ bv, unsigned short* __restrict__ vout)
{
    __shared__ alignas(16) unsigned short lds_raw[20480];   // 40960 B
    unsigned short* lds_w = lds_raw;                  // [2][128*PAD]
    unsigned short* lds_x = lds_raw + 2 * 128 * PAD;  // [2][128*PAD]
    unsigned short* lds_ep = lds_raw;                 // [128][EP2] reused

    const int tid = threadIdx.x;
    const int lane = tid & 63;
    const int wave = tid >> 6;       // 0..3
    const int wn = wave & 1;         // n0w = wn*64
    const int wm = wave >> 1;        // m0w = wm*64
    const int la = lane & 15;
    const int lg = lane >> 4;

    // XCD-chunked bijective swizzle (4200 % 8 == 0, 525 per XCD):
    // consecutive lin on one XCD -> n-tile pairs (2k,2k+1) share the XCD L2.
    const int orig = blockIdx.x;
    const int xcd = orig & 7, lin = orig >> 3;
    const int bid = xcd * 525 + lin;
    const int n0 = (bid & 1) * 128;
    const long row0 = (long)(bid >> 1) * BM;

    // staging: row = tid/2 (0..127), k-seg = (tid&1)*16
    const int sr = tid >> 1;
    const int sk = (tid & 1) * 16;
    const unsigned short* wptr = WvT + (size_t)(n0 + sr) * CDIM + sk;
    const float* xptr = value + (row0 + sr) * (long)CDIM + sk;

    u16x8 wrg[2];
    f32x4 xrg[4];

    auto load_tile = [&](int kb) {
        const u16x8* qw = (const u16x8*)(wptr + kb);
        wrg[0] = qw[0]; wrg[1] = qw[1];
        const float* p = xptr + kb;
        xrg[0] = *(const f32x4*)(p);
        xrg[1] = *(const f32x4*)(p + 4);
        xrg[2] = *(const f32x4*)(p + 8);
        xrg[3] = *(const f32x4*)(p + 12);
    };
    auto write_tile = [&](int buf) {
        u16x8* ww = (u16x8*)&lds_w[buf * (128 * PAD) + sr * PAD + sk];
        ww[0] = wrg[0]; ww[1] = wrg[1];
        u16x8 t0, t1;
#pragma unroll
        for (int i = 0; i < 4; ++i) {
            t0[i]     = f2bf(xrg[0][i]);
            t0[i + 4] = f2bf(xrg[1][i]);
            t1[i]     = f2bf(xrg[2][i]);
            t1[i + 4] = f2bf(xrg[3][i]);
        }
        u16x8* wx = (u16x8*)&lds_x[buf * (128 * PAD) + sr * PAD + sk];
        wx[0] = t0; wx[1] = t1;
    };

    f32x4 acc[4][4] = {};    // [n-frag][m-frag]

    load_tile(0);
    write_tile(0);
    __syncthreads();
    int cur = 0;

    for (int t = 0; t < NT; ++t) {
        if (t + 1 < NT) load_tile((t + 1) * BK);

        const unsigned short* pw = &lds_w[cur * (128 * PAD) + (wn * 64 + la) * PAD + lg * 8];
        const unsigned short* px = &lds_x[cur * (128 * PAD) + (wm * 64 + la) * PAD + lg * 8];
        short8 xf[4];
#pragma unroll
        for (int mf = 0; mf < 4; ++mf)
            xf[mf] = *(const short8*)(px + mf * 16 * PAD);
#pragma unroll
        for (int nf = 0; nf < 4; ++nf) {
            const short8 wf = *(const short8*)(pw + nf * 16 * PAD);
#pragma unroll
            for (int mf = 0; mf < 4; ++mf)
                acc[nf][mf] = __builtin_amdgcn_mfma_f32_16x16x32_bf16(wf, xf[mf], acc[nf][mf], 0, 0, 0);
        }

        if (t + 1 < NT) write_tile(cur ^ 1);
        __syncthreads();
        cur ^= 1;
    }

    // epilogue: 128x128 tile through LDS -> coalesced 128B/thread stores
    // (loop's final barrier guarantees all staging reads are done)
#pragma unroll
    for (int nf = 0; nf < 4; ++nf) {
        const int nbl = wn * 64 + nf * 16 + lg * 4;       // 0..127 local col
        const f32x4 bb = *(const f32x4*)&bv[n0 + nbl];
#pragma unroll
        for (int mf = 0; mf < 4; ++mf) {
            const int mloc = wm * 64 + mf * 16 + la;      // 0..127 local row
            u16x4 o;
#pragma unroll
            for (int j = 0; j < 4; ++j) o[j] = f2bf(acc[nf][mf][j] + bb[j]);
            *(u16x4*)&lds_ep[mloc * EP2 + nbl] = o;
        }
    }
    __syncthreads();
    {
        const int er = tid >> 1;            // 0..127
        const int ec = (tid & 1) * 64;      // 0 or 64
        const u16x8* src = (const u16x8*)&lds_ep[er * EP2 + ec];
        u16x8* dst = (u16x8*)&vout[(row0 + er) * CDIM + n0 + ec];
#pragma unroll
        for (int i = 0; i < 8; ++i) dst[i] = src[i];
    }
}

// ---------------------------------------------------------------------------
// Kernel OA: offatt = query @ [Woff ; Watt] + bias  -> f32 [BS*LQ][288]
// ---------------------------------------------------------------------------
#define APAD 40
#define BPAD 40

__global__ __launch_bounds__(256) void offatt_gemm_mfma(
    const float* __restrict__ query, const unsigned short* __restrict__ WoaT,
    const float* __restrict__ boff, const float* __restrict__ batt,
    float* __restrict__ offatt)
{
    __shared__ unsigned short lds_a[2][BM * APAD];
    __shared__ unsigned short lds_b[2][NOA * BPAD];

    const int tid = threadIdx.x;
    const int lane = tid & 63;
    const int wave = tid >> 6;
    const int wm = wave >> 1;
    const int wn = wave & 1;
    const long row0 = (long)blockIdx.x * BM;

    const int ar = tid >> 1;
    const int ak = (tid & 1) * 16;
    const float* aptr = query + (row0 + ar) * CDIM + ak;
    const unsigned short* bptr  = WoaT + (size_t)tid * CDIM;
    const unsigned short* bptr2 = WoaT + (size_t)(256 + tid) * CDIM;
    const bool extra = tid < 32;

    f32x4 arg[4];
    u16x8 brg[4], brg2[4];

    auto load_tile = [&](int kb) {
        const float* p = aptr + kb;
        arg[0] = *(const f32x4*)(p);
        arg[1] = *(const f32x4*)(p + 4);
        arg[2] = *(const f32x4*)(p + 8);
        arg[3] = *(const f32x4*)(p + 12);
        const u16x8* q = (const u16x8*)(bptr + kb);
        brg[0] = q[0]; brg[1] = q[1]; brg[2] = q[2]; brg[3] = q[3];
        if (extra) {
            const u16x8* q2 = (const u16x8*)(bptr2 + kb);
            brg2[0] = q2[0]; brg2[1] = q2[1]; brg2[2] = q2[2]; brg2[3] = q2[3];
        }
    };
    auto write_tile = [&](int buf) {
        u16x8 t0, t1;
#pragma unroll
        for (int i = 0; i < 4; ++i) {
            t0[i]     = f2bf(arg[0][i]);
            t0[i + 4] = f2bf(arg[1][i]);
            t1[i]     = f2bf(arg[2][i]);
            t1[i + 4] = f2bf(arg[3][i]);
        }
        u16x8* wa = (u16x8*)&lds_a[buf][ar * APAD + ak];
        wa[0] = t0; wa[1] = t1;
        u16x8* wb = (u16x8*)&lds_b[buf][tid * BPAD];
        wb[0] = brg[0]; wb[1] = brg[1]; wb[2] = brg[2]; wb[3] = brg[3];
        if (extra) {
            u16x8* wb2 = (u16x8*)&lds_b[buf][(256 + tid) * BPAD];
            wb2[0] = brg2[0]; wb2[1] = brg2[1]; wb2[2] = brg2[2]; wb2[3] = brg2[3];
        }
    };

    f32x4 acc[4][9] = {};
    const int la = lane & 15;
    const int lg = lane >> 4;

    load_tile(0);
    write_tile(0);
    __syncthreads();
    int cur = 0;

    for (int t = 0; t < CDIM / BK; ++t) {
        if (t + 1 < CDIM / BK) load_tile((t + 1) * BK);

        const unsigned short* pa = &lds_a[cur][(wm * 64 + la) * APAD + lg * 8];
        const unsigned short* pb = &lds_b[cur][(wn * 144 + la) * BPAD + lg * 8];
        short8 af[4];
#pragma unroll
        for (int mi = 0; mi < 4; ++mi)
            af[mi] = *(const short8*)(pa + mi * 16 * APAD);
#pragma unroll
        for (int ni = 0; ni < 9; ++ni) {
            const short8 bf = *(const short8*)(pb + ni * 16 * BPAD);
#pragma unroll
            for (int mi = 0; mi < 4; ++mi)
                acc[mi][ni] = __builtin_amdgcn_mfma_f32_16x16x32_bf16(af[mi], bf, acc[mi][ni], 0, 0, 0);
        }

        if (t + 1 < CDIM / BK) write_tile(cur ^ 1);
        __syncthreads();
        cur ^= 1;
    }

    float bias[9];
#pragma unroll
    for (int ni = 0; ni < 9; ++ni) {
        const int col = wn * 144 + ni * 16 + la;
        bias[ni] = (col < 192) ? boff[col] : batt[col - 192];
    }
#pragma unroll
    for (int mi = 0; mi < 4; ++mi) {
#pragma unroll
        for (int ni = 0; ni < 9; ++ni) {
            const int col = wn * 144 + ni * 16 + la;
#pragma unroll
            for (int j = 0; j < 4; ++j) {
                const long r = row0 + wm * 64 + mi * 16 + lg * 4 + j;
                offatt[r * NOA + col] = acc[mi][ni][j] + bias[ni];
            }
        }
    }
}

// ---------------------------------------------------------------------------
// Kernel B: softmax + locations + vectorized bilinear gather.
// XCD-grouping swizzle keeps one batch's v-slice L2-resident per XCD.
// ---------------------------------------------------------------------------
__global__ __launch_bounds__(256) void sample_kernel(
    const float* __restrict__ offatt, const float* __restrict__ refpts,
    const unsigned short* __restrict__ v, unsigned short* __restrict__ mid)
{
    __shared__ float oa_s[NOA];
    __shared__ float aw_s[96];
    __shared__ float px_s[96];
    __shared__ float py_s[96];

    const int tid = threadIdx.x;
    const int nb = blockIdx.x;
    const int x = nb & 7;
    const int rest = nb >> 3;          // 0..1199
    const int g = rest / LQ;           // 0..3
    const int q = rest % LQ;
    const int b = g * 8 + x;
    const long bq = (long)b * LQ + q;

    oa_s[tid] = offatt[bq * NOA + tid];
    if (tid < 32) oa_s[256 + tid] = offatt[bq * NOA + 256 + tid];
    __syncthreads();

    if (tid < 8) {
        float m = -1e30f;
#pragma unroll
        for (int i = 0; i < 12; ++i) m = fmaxf(m, oa_s[192 + tid * 12 + i]);
        float e[12];
        float s = 0.f;
#pragma unroll
        for (int i = 0; i < 12; ++i) { e[i] = __expf(oa_s[192 + tid * 12 + i] - m); s += e[i]; }
        const float inv = 1.f / s;
#pragma unroll
        for (int i = 0; i < 12; ++i) aw_s[tid * 12 + i] = e[i] * inv;
    }
    if (tid >= 128 && tid < 224) {
        const int t = tid - 128;
        const int h = t / 12, idx = t % 12, l = idx >> 2, p = idx & 3;
        const float* rp = refpts + (bq * NLEVELS + l) * 4;
        const float rx = rp[0], ry = rp[1], rw = rp[2], rh = rp[3];
        const float ox = oa_s[((h * NLEVELS + l) * NPOINTS + p) * 2 + 0];
        const float oy = oa_s[((h * NLEVELS + l) * NPOINTS + p) * 2 + 1];
        const float lx = rx + ox * 0.125f * rw;
        const float ly = ry + oy * 0.125f * rh;
        const int Wl = 80 >> l;
        px_s[t] = lx * (float)Wl - 0.5f;
        py_s[t] = ly * (float)Wl - 0.5f;
    }
    __syncthreads();

    const int h = tid >> 5;
    const int pg = (tid >> 3) & 3;
    const int d4 = tid & 7;
    const unsigned short* vb = v + ((size_t)b * LV) * CDIM + h * HD + d4 * 4;

    float a0 = 0.f, a1 = 0.f, a2 = 0.f, a3 = 0.f;
#pragma unroll
    for (int j = 0; j < 3; ++j) {
        const int i = pg * 3 + j;
        const int l = i >> 2;
        const int idx = h * 12 + i;
        const float px = px_s[idx], py = py_s[idx], aw = aw_s[idx];
        const int Wl = 80 >> l;
        const int start = (l == 0) ? 0 : (l == 1) ? 6400 : 8000;

        const float fx = floorf(px), fy = floorf(py);
        const int x0 = (int)fx, y0 = (int)fy;
        const float wx1 = px - fx, wy1 = py - fy;
        const float wx0 = 1.f - wx1, wy0 = 1.f - wy1;
        const float w00 = wx0 * wy0 * aw, w10 = wx1 * wy0 * aw;
        const float w01 = wx0 * wy1 * aw, w11 = wx1 * wy1 * aw;
        const bool x0v = (unsigned)x0 < (unsigned)Wl;
        const bool x1v = (unsigned)(x0 + 1) < (unsigned)Wl;
        const bool y0v = (unsigned)y0 < (unsigned)Wl;
        const bool y1v = (unsigned)(y0 + 1) < (unsigned)Wl;

        const unsigned short* base = vb + (size_t)start * CDIM;
        if (y0v) {
            const unsigned short* r0p = base + (size_t)(y0 * Wl) * CDIM;
            if (x0v) {
                const u16x4 u = *(const u16x4*)(r0p + (size_t)x0 * CDIM);
                a0 = fmaf(w00, bf2f(u[0]), a0); a1 = fmaf(w00, bf2f(u[1]), a1);
                a2 = fmaf(w00, bf2f(u[2]), a2); a3 = fmaf(w00, bf2f(u[3]), a3);
            }
            if (x1v) {
                const u16x4 u = *(const u16x4*)(r0p + (size_t)(x0 + 1) * CDIM);
                a0 = fmaf(w10, bf2f(u[0]), a0); a1 = fmaf(w10, bf2f(u[1]), a1);
                a2 = fmaf(w10, bf2f(u[2]), a2); a3 = fmaf(w10, bf2f(u[3]), a3);
            }
        }
        if (y1v) {
            const unsigned short* r1p = base + (size_t)((y0 + 1) * Wl) * CDIM;
            if (x0v) {
                const u16x4 u = *(const u16x4*)(r1p + (size_t)x0 * CDIM);
                a0 = fmaf(w01, bf2f(u[0]), a0); a1 = fmaf(w01, bf2f(u[1]), a1);
                a2 = fmaf(w01, bf2f(u[2]), a2); a3 = fmaf(w01, bf2f(u[3]), a3);
            }
            if (x1v) {
                const u16x4 u = *(const u16x4*)(r1p + (size_t)(x0 + 1) * CDIM);
                a0 = fmaf(w11, bf2f(u[0]), a0); a1 = fmaf(w11, bf2f(u[1]), a1);
                a2 = fmaf(w11, bf2f(u[2]), a2); a3 = fmaf(w11, bf2f(u[3]), a3);
            }
        }
    }

    a0 += __shfl_xor(a0, 8);  a1 += __shfl_xor(a1, 8);
    a2 += __shfl_xor(a2, 8);  a3 += __shfl_xor(a3, 8);
    a0 += __shfl_xor(a0, 16); a1 += __shfl_xor(a1, 16);
    a2 += __shfl_xor(a2, 16); a3 += __shfl_xor(a3, 16);

    if (pg == 0) {
        u16x4 o;
        o[0] = f2bf(a0); o[1] = f2bf(a1); o[2] = f2bf(a2); o[3] = f2bf(a3);
        *(u16x4*)&mid[bq * CDIM + h * HD + d4 * 4] = o;
    }
}

// ---------------------------------------------------------------------------
// Kernel C: out = mid(bf16) @ Wout + bout -> f32, swapped roles, float4 stores.
// ---------------------------------------------------------------------------
__global__ __launch_bounds__(256) void out_gemm_mfma(
    const unsigned short* __restrict__ mid, const unsigned short* __restrict__ WoutT,
    const float* __restrict__ bout, float* __restrict__ out)
{
    __shared__ unsigned short lds_w[2][256 * APAD];
    __shared__ unsigned short lds_x[2][BM * BPAD];

    const int tid = threadIdx.x;
    const int lane = tid & 63;
    const int wave = tid >> 6;
    const int wn = wave & 1;
    const int wm = wave >> 1;
    const long row0 = (long)blockIdx.x * BM;

    const unsigned short* wptr = WoutT + (size_t)tid * CDIM;
    const int xr = tid >> 1;
    const int xk = (tid & 1) * 16;
    const unsigned short* xptr = mid + (row0 + xr) * CDIM + xk;

    u16x8 wrg[4];
    u16x8 xrg[2];

    auto load_tile = [&](int kb) {
        const u16x8* qw = (const u16x8*)(wptr + kb);
        wrg[0] = qw[0]; wrg[1] = qw[1]; wrg[2] = qw[2]; wrg[3] = qw[3];
        const u16x8* qx = (const u16x8*)(xptr + kb);
        xrg[0] = qx[0]; xrg[1] = qx[1];
    };
    auto write_tile = [&](int buf) {
        u16x8* ww = (u16x8*)&lds_w[buf][tid * APAD];
        ww[0] = wrg[0]; ww[1] = wrg[1]; ww[2] = wrg[2]; ww[3] = wrg[3];
        u16x8* wx = (u16x8*)&lds_x[buf][xr * BPAD + xk];
        wx[0] = xrg[0]; wx[1] = xrg[1];
    };

    f32x4 acc[8][4] = {};
    const int la = lane & 15;
    const int lg = lane >> 4;

    load_tile(0);
    write_tile(0);
    __syncthreads();
    int cur = 0;

    for (int t = 0; t < CDIM / BK; ++t) {
        if (t + 1 < CDIM / BK) load_tile((t + 1) * BK);

        const unsigned short* pw = &lds_w[cur][(wn * 128 + la) * APAD + lg * 8];
        const unsigned short* px = &lds_x[cur][(wm * 64 + la) * BPAD + lg * 8];
        short8 xf[4];
#pragma unroll
        for (int mf = 0; mf < 4; ++mf)
            xf[mf] = *(const short8*)(px + mf * 16 * BPAD);
#pragma unroll
        for (int nf = 0; nf < 8; ++nf) {
            const short8 wf = *(const short8*)(pw + nf * 16 * APAD);
#pragma unroll
            for (int mf = 0; mf < 4; ++mf)
                acc[nf][mf] = __builtin_amdgcn_mfma_f32_16x16x32_bf16(wf, xf[mf], acc[nf][mf], 0, 0, 0);
        }

        if (t + 1 < CDIM / BK) write_tile(cur ^ 1);
        __syncthreads();
        cur ^= 1;
    }

#pragma unroll
    for (int nf = 0; nf < 8; ++nf) {
        const int nbase = wn * 128 + nf * 16 + lg * 4;
        const f32x4 bb = *(const f32x4*)&bout[nbase];
#pragma unroll
        for (int mf = 0; mf < 4; ++mf) {
            const long m = row0 + wm * 64 + mf * 16 + la;
            f32x4 o;
#pragma unroll
            for (int j = 0; j < 4; ++j) o[j] = acc[nf][mf][j] + bb[j];
            *(f32x4*)&out[m * CDIM + nbase] = o;
        }
    }
}

extern "C" void kernel_launch(void* const* d_in, const int* in_sizes, int n_in,
                              void* d_out, int out_size, void* d_ws, size_t ws_size,
                              hipStream_t stream) {
    const float* query = (const float*)d_in[0];
    const float* refp  = (const float*)d_in[1];
    const float* value = (const float*)d_in[2];
    const float* Wv    = (const float*)d_in[3];
    const float* bv    = (const float*)d_in[4];
    const float* Woff  = (const float*)d_in[5];
    const float* boff  = (const float*)d_in[6];
    const float* Watt  = (const float*)d_in[7];
    const float* batt  = (const float*)d_in[8];
    const float* Wout  = (const float*)d_in[9];
    const float* bout  = (const float*)d_in[10];
    float* out = (float*)d_out;

    char* ws = (char*)d_ws;
    unsigned short* v = (unsigned short*)ws;                        // bf16 [BS*LV][256]
    size_t off = (size_t)BS * LV * CDIM * 2;                        // 137,625,600
    float* offatt = (float*)(ws + off);                             // f32 [9600][288]
    off += (size_t)BS * LQ * NOA * 4;                               // +11,059,200
    unsigned short* mid = (unsigned short*)(ws + off);              // bf16 [9600][256]
    off += (size_t)BS * LQ * CDIM * 2;                              // +4,915,200
    unsigned short* WvT = (unsigned short*)(ws + off);
    off += 256 * 256 * 2;
    unsigned short* WoaT = (unsigned short*)(ws + off);
    off += NOA * 256 * 2;
    unsigned short* WoutT = (unsigned short*)(ws + off);

    prep_weights_kernel<<<800, 256, 0, stream>>>(Wv, Wout, Woff, Watt, WvT, WoutT, WoaT);
    proj_value_mfma<<<(BS * LV) / BM * 2, 256, 0, stream>>>(value, WvT, bv, v);
    offatt_gemm_mfma<<<(BS * LQ) / BM, 256, 0, stream>>>(query, WoaT, boff, batt, offatt);
    sample_kernel<<<BS * LQ, 256, 0, stream>>>(offatt, refp, v, mid);
    out_gemm_mfma<<<(BS * LQ) / BM, 256, 0, stream>>>(mid, WoutT, bout, out);
}

// Round 15
// 202.386 us; speedup vs baseline: 1.0679x; 1.0679x over previous
//
#include <hip/hip_runtime.h>
#include <hip/hip_bf16.h>

#define BS 32
#define LQ 300
#define CDIM 256
#define HEADS 8
#define HD 32
#define NLEVELS 3
#define NPOINTS 4
#define LV 8400   // 80*80 + 40*40 + 20*20
#define NOA 288   // 192 offset cols + 96 att cols

typedef __attribute__((ext_vector_type(4))) float f32x4;
typedef __attribute__((ext_vector_type(8))) short short8;
typedef __attribute__((ext_vector_type(8))) unsigned short u16x8;
typedef __attribute__((ext_vector_type(4))) unsigned short u16x4;

__device__ __forceinline__ unsigned short f2bf(float f) {
    __hip_bfloat16 h = __float2bfloat16(f);
    return __bfloat16_as_ushort(h);
}
__device__ __forceinline__ float bf2f(unsigned short u) {
    union { unsigned u; float f; } v; v.u = ((unsigned)u) << 16;
    return v.f;
}
__device__ __forceinline__ short8 cvt8(const f32x4 a, const f32x4 b) {
    u16x8 c;
#pragma unroll
    for (int i = 0; i < 4; ++i) { c[i] = f2bf(a[i]); c[i + 4] = f2bf(b[i]); }
    union { u16x8 u; short8 s; } v; v.u = c; return v.s;
}
__device__ __forceinline__ void gload16(const void* g, void* l) {
    __builtin_amdgcn_global_load_lds(
        (const __attribute__((address_space(1))) void*)g,
        (__attribute__((address_space(3))) void*)l, 16, 0, 0);
}

// ---------------------------------------------------------------------------
// Prep (fused): WvT (PRE-SWIZZLED for proj), WoutT, WoaT.  grid = 800.
// WvT row n stores k at kd: 8-byte half (k>>2)&7 XOR'd with (n&7) within each
// 32-elem window — so proj's LINEAR global_load_lds lands a bank-swizzled
// LDS layout (reads become 2-way = free).  Exact permutation, no numerics.
// ---------------------------------------------------------------------------
__global__ void prep_weights_kernel(
    const float* __restrict__ Wv, const float* __restrict__ Wout,
    const float* __restrict__ Woff, const float* __restrict__ Watt,
    unsigned short* __restrict__ WvT, unsigned short* __restrict__ WoutT,
    unsigned short* __restrict__ WoaT)
{
    const int bid = blockIdx.x;
    const int k = threadIdx.x;
    if (bid < 256) {
        const int n = bid;
        const int kd = (k & ~31) | ((((k >> 2) & 7) ^ (n & 7)) << 2) | (k & 3);
        WvT[n * 256 + kd] = f2bf(Wv[k * 256 + n]);
    } else if (bid < 512) {
        const int n = bid - 256;
        WoutT[n * 256 + k] = f2bf(Wout[k * 256 + n]);
    } else {
        const int n = bid - 512;
        const float w = (n < 192) ? Woff[k * 192 + n] : Watt[k * 96 + (n - 192)];
        WoaT[n * 256 + k] = f2bf(w);
    }
}

#define BM 128
#define BK 32
#define EP2 136    // proj epilogue row stride (272 B, 16B-aligned)
#define NT (CDIM / BK)
#define TSLOT 24576          // per-tile LDS: X f32 16 KB + W bf16 8 KB
#define WOFF 16384
#define PROJ_LDS (3 * TSLOT) // 73728 B dynamic -> 2 blocks/CU

// ---------------------------------------------------------------------------
// Kernel A: v = bf16( value @ Wv + bv ), swapped roles:
// D[n][m] = WvT(n,k) x value^T(k,m).
// 3-DEEP global_load_lds PIPELINE with COUNTED vmcnt (T3+T4, m201 pattern):
// per K-step: {vmcnt(6) -> tile t arrived (its 6 gloads are the oldest);
// raw s_barrier (no vmcnt(0) drain!); issue tile t+2 (gloads, zero VGPRs);
// compute tile t}.  Pipeline state lives in LDS + vmcnt counter, so hipcc's
// register-prefetch serialization (rounds 5/8/9/12, VGPR 40-72) is irrelevant.
// X stored f32 (gload can't convert; cvt_pk on LDS->reg), source-address
// swizzled per-lane (m173); W pre-swizzled in prep -> straight linear copy.
// All LDS reads ~2-way (free).  BM=128 x BN=128, 4 waves 2x2, acc[4][4].
// ---------------------------------------------------------------------------
__global__ __launch_bounds__(256, 2) void proj_value_mfma(
    const float* __restrict__ value, const unsigned short* __restrict__ WvT,
    const float* __restrict__ bv, unsigned short* __restrict__ vout)
{
    extern __shared__ char dlds[];

    const int tid = threadIdx.x;
    const int lane = tid & 63;
    const int wave = tid >> 6;       // 0..3
    const int wn = wave & 1;         // n0w = wn*64
    const int wm = wave >> 1;        // m0w = wm*64
    const int la = lane & 15;
    const int lg = lane >> 4;
    const int l = lane;

    // XCD-chunked bijective swizzle (4200 % 8 == 0, 525/XCD): the two n-tiles
    // of one m-tile are consecutive on the same XCD -> X re-read is L2-local.
    const int orig = blockIdx.x;
    const int xcd = orig & 7, lin = orig >> 3;
    const int bid = xcd * 525 + lin;
    const int n0 = (bid & 1) * 128;
    const long row0 = (long)(bid >> 1) * BM;

    // per-lane gload sources (c advances rows; t advances the 32-wide K window)
    // X: gload c covers LDS rows (wave*4+c)*8 + l/8, 16B slot l&7; source slot
    //    pre-swizzled: (l&7) ^ (l>>3)  [= slot ^ (row&7)]
    const float* xsrc = value + (row0 + wave * 32 + (l >> 3)) * (long)CDIM
                        + ((l & 7) ^ (l >> 3)) * 4;
    // W: data pre-swizzled in WvT -> straight linear copy
    const unsigned short* wsrc = WvT + (size_t)(n0 + wave * 32 + (l >> 2)) * CDIM
                                 + (l & 3) * 8;

    auto issue = [&](int slot, int t) {
        char* sb = dlds + slot * TSLOT;
        const float* xs = xsrc + t * 32;
        char* xd = sb + wave * 4096;
#pragma unroll
        for (int c = 0; c < 4; ++c)
            gload16(xs + c * 2048, xd + c * 1024);
        const unsigned short* wsp = wsrc + t * 32;
        char* wd = sb + WOFF + wave * 2048;
#pragma unroll
        for (int c = 0; c < 2; ++c)
            gload16(wsp + c * 4096, wd + c * 1024);
    };

    f32x4 acc[4][4] = {};    // [n-frag][m-frag]

    auto compute = [&](int slot) {
        const char* sb = dlds + slot * TSLOT;
        short8 xf[4];
#pragma unroll
        for (int mf = 0; mf < 4; ++mf) {
            const int row = wm * 64 + mf * 16 + la;
            const char* xb = sb + row * 128;
            const f32x4 a = *(const f32x4*)(xb + (((2 * lg)     ^ (la & 7)) * 16));
            const f32x4 b = *(const f32x4*)(xb + (((2 * lg + 1) ^ (la & 7)) * 16));
            xf[mf] = cvt8(a, b);
        }
#pragma unroll
        for (int nf = 0; nf < 4; ++nf) {
            const int row = wn * 64 + nf * 16 + la;
            const char* wb = sb + WOFF + row * 64;
            union { unsigned long long q[2]; short8 s; } wu;
            wu.q[0] = *(const unsigned long long*)(wb + (((2 * lg)     ^ (la & 7)) * 8));
            wu.q[1] = *(const unsigned long long*)(wb + (((2 * lg + 1) ^ (la & 7)) * 8));
#pragma unroll
            for (int mf = 0; mf < 4; ++mf)
                acc[nf][mf] = __builtin_amdgcn_mfma_f32_16x16x32_bf16(
                    wu.s, xf[mf], acc[nf][mf], 0, 0, 0);
        }
    };

    // prologue: tiles 0,1 in flight (6 gloads each)
    issue(0, 0);
    issue(1, 1);

#pragma unroll
    for (int t = 0; t < NT; ++t) {
        if (t < NT - 1) { asm volatile("s_waitcnt vmcnt(6)" ::: "memory"); }
        else            { asm volatile("s_waitcnt vmcnt(0)" ::: "memory"); }
        __builtin_amdgcn_s_barrier();   // raw: no vmcnt(0) drain
        if (t + 2 < NT) issue((t + 2) % 3, t + 2);
        compute(t % 3);
    }

    // epilogue: 128x128 tile through LDS -> coalesced 128B/thread stores
    __syncthreads();   // all LDS reads done before reuse
    {
        unsigned short* lds_ep = (unsigned short*)dlds;
#pragma unroll
        for (int nf = 0; nf < 4; ++nf) {
            const int nbl = wn * 64 + nf * 16 + lg * 4;
            const f32x4 bb = *(const f32x4*)&bv[n0 + nbl];
#pragma unroll
            for (int mf = 0; mf < 4; ++mf) {
                const int mloc = wm * 64 + mf * 16 + la;
                u16x4 o;
#pragma unroll
                for (int j = 0; j < 4; ++j) o[j] = f2bf(acc[nf][mf][j] + bb[j]);
                *(u16x4*)&lds_ep[mloc * EP2 + nbl] = o;
            }
        }
        __syncthreads();
        const int er = tid >> 1;            // 0..127
        const int ec = (tid & 1) * 64;      // 0 or 64
        const u16x8* src = (const u16x8*)&lds_ep[er * EP2 + ec];
        u16x8* dst = (u16x8*)&vout[(row0 + er) * CDIM + n0 + ec];
#pragma unroll
        for (int i = 0; i < 8; ++i) dst[i] = src[i];
    }
}

// ---------------------------------------------------------------------------
// Kernel OA: offatt = query @ [Woff ; Watt] + bias  -> f32 [BS*LQ][288]
// ---------------------------------------------------------------------------
#define APAD 40
#define BPAD 40

__global__ __launch_bounds__(256) void offatt_gemm_mfma(
    const float* __restrict__ query, const unsigned short* __restrict__ WoaT,
    const float* __restrict__ boff, const float* __restrict__ batt,
    float* __restrict__ offatt)
{
    __shared__ unsigned short lds_a[2][BM * APAD];
    __shared__ unsigned short lds_b[2][NOA * BPAD];

    const int tid = threadIdx.x;
    const int lane = tid & 63;
    const int wave = tid >> 6;
    const int wm = wave >> 1;
    const int wn = wave & 1;
    const long row0 = (long)blockIdx.x * BM;

    const int ar = tid >> 1;
    const int ak = (tid & 1) * 16;
    const float* aptr = query + (row0 + ar) * CDIM + ak;
    const unsigned short* bptr  = WoaT + (size_t)tid * CDIM;
    const unsigned short* bptr2 = WoaT + (size_t)(256 + tid) * CDIM;
    const bool extra = tid < 32;

    f32x4 arg[4];
    u16x8 brg[4], brg2[4];

    auto load_tile = [&](int kb) {
        const float* p = aptr + kb;
        arg[0] = *(const f32x4*)(p);
        arg[1] = *(const f32x4*)(p + 4);
        arg[2] = *(const f32x4*)(p + 8);
        arg[3] = *(const f32x4*)(p + 12);
        const u16x8* q = (const u16x8*)(bptr + kb);
        brg[0] = q[0]; brg[1] = q[1]; brg[2] = q[2]; brg[3] = q[3];
        if (extra) {
            const u16x8* q2 = (const u16x8*)(bptr2 + kb);
            brg2[0] = q2[0]; brg2[1] = q2[1]; brg2[2] = q2[2]; brg2[3] = q2[3];
        }
    };
    auto write_tile = [&](int buf) {
        u16x8 t0, t1;
#pragma unroll
        for (int i = 0; i < 4; ++i) {
            t0[i]     = f2bf(arg[0][i]);
            t0[i + 4] = f2bf(arg[1][i]);
            t1[i]     = f2bf(arg[2][i]);
            t1[i + 4] = f2bf(arg[3][i]);
        }
        u16x8* wa = (u16x8*)&lds_a[buf][ar * APAD + ak];
        wa[0] = t0; wa[1] = t1;
        u16x8* wb = (u16x8*)&lds_b[buf][tid * BPAD];
        wb[0] = brg[0]; wb[1] = brg[1]; wb[2] = brg[2]; wb[3] = brg[3];
        if (extra) {
            u16x8* wb2 = (u16x8*)&lds_b[buf][(256 + tid) * BPAD];
            wb2[0] = brg2[0]; wb2[1] = brg2[1]; wb2[2] = brg2[2]; wb2[3] = brg2[3];
        }
    };

    f32x4 acc[4][9] = {};
    const int la = lane & 15;
    const int lg = lane >> 4;

    load_tile(0);
    write_tile(0);
    __syncthreads();
    int cur = 0;

    for (int t = 0; t < CDIM / BK; ++t) {
        if (t + 1 < CDIM / BK) load_tile((t + 1) * BK);

        const unsigned short* pa = &lds_a[cur][(wm * 64 + la) * APAD + lg * 8];
        const unsigned short* pb = &lds_b[cur][(wn * 144 + la) * BPAD + lg * 8];
        short8 af[4];
#pragma unroll
        for (int mi = 0; mi < 4; ++mi)
            af[mi] = *(const short8*)(pa + mi * 16 * APAD);
#pragma unroll
        for (int ni = 0; ni < 9; ++ni) {
            const short8 bf = *(const short8*)(pb + ni * 16 * BPAD);
#pragma unroll
            for (int mi = 0; mi < 4; ++mi)
                acc[mi][ni] = __builtin_amdgcn_mfma_f32_16x16x32_bf16(af[mi], bf, acc[mi][ni], 0, 0, 0);
        }

        if (t + 1 < CDIM / BK) write_tile(cur ^ 1);
        __syncthreads();
        cur ^= 1;
    }

    float bias[9];
#pragma unroll
    for (int ni = 0; ni < 9; ++ni) {
        const int col = wn * 144 + ni * 16 + la;
        bias[ni] = (col < 192) ? boff[col] : batt[col - 192];
    }
#pragma unroll
    for (int mi = 0; mi < 4; ++mi) {
#pragma unroll
        for (int ni = 0; ni < 9; ++ni) {
            const int col = wn * 144 + ni * 16 + la;
#pragma unroll
            for (int j = 0; j < 4; ++j) {
                const long r = row0 + wm * 64 + mi * 16 + lg * 4 + j;
                offatt[r * NOA + col] = acc[mi][ni][j] + bias[ni];
            }
        }
    }
}

// ---------------------------------------------------------------------------
// Kernel B: softmax + locations + vectorized bilinear gather.
// ---------------------------------------------------------------------------
__global__ __launch_bounds__(256) void sample_kernel(
    const float* __restrict__ offatt, const float* __restrict__ refpts,
    const unsigned short* __restrict__ v, unsigned short* __restrict__ mid)
{
    __shared__ float oa_s[NOA];
    __shared__ float aw_s[96];
    __shared__ float px_s[96];
    __shared__ float py_s[96];

    const int tid = threadIdx.x;
    const int nb = blockIdx.x;
    const int x = nb & 7;
    const int rest = nb >> 3;          // 0..1199
    const int g = rest / LQ;           // 0..3
    const int q = rest % LQ;
    const int b = g * 8 + x;
    const long bq = (long)b * LQ + q;

    oa_s[tid] = offatt[bq * NOA + tid];
    if (tid < 32) oa_s[256 + tid] = offatt[bq * NOA + 256 + tid];
    __syncthreads();

    if (tid < 8) {
        float m = -1e30f;
#pragma unroll
        for (int i = 0; i < 12; ++i) m = fmaxf(m, oa_s[192 + tid * 12 + i]);
        float e[12];
        float s = 0.f;
#pragma unroll
        for (int i = 0; i < 12; ++i) { e[i] = __expf(oa_s[192 + tid * 12 + i] - m); s += e[i]; }
        const float inv = 1.f / s;
#pragma unroll
        for (int i = 0; i < 12; ++i) aw_s[tid * 12 + i] = e[i] * inv;
    }
    if (tid >= 128 && tid < 224) {
        const int t = tid - 128;
        const int h = t / 12, idx = t % 12, lvl = idx >> 2, p = idx & 3;
        const float* rp = refpts + (bq * NLEVELS + lvl) * 4;
        const float rx = rp[0], ry = rp[1], rw = rp[2], rh = rp[3];
        const float ox = oa_s[((h * NLEVELS + lvl) * NPOINTS + p) * 2 + 0];
        const float oy = oa_s[((h * NLEVELS + lvl) * NPOINTS + p) * 2 + 1];
        const float lx = rx + ox * 0.125f * rw;
        const float ly = ry + oy * 0.125f * rh;
        const int Wl = 80 >> lvl;
        px_s[t] = lx * (float)Wl - 0.5f;
        py_s[t] = ly * (float)Wl - 0.5f;
    }
    __syncthreads();

    const int h = tid >> 5;
    const int pg = (tid >> 3) & 3;
    const int d4 = tid & 7;
    const unsigned short* vb = v + ((size_t)b * LV) * CDIM + h * HD + d4 * 4;

    float a0 = 0.f, a1 = 0.f, a2 = 0.f, a3 = 0.f;
#pragma unroll
    for (int j = 0; j < 3; ++j) {
        const int i = pg * 3 + j;
        const int lvl = i >> 2;
        const int idx = h * 12 + i;
        const float px = px_s[idx], py = py_s[idx], aw = aw_s[idx];
        const int Wl = 80 >> lvl;
        const int start = (lvl == 0) ? 0 : (lvl == 1) ? 6400 : 8000;

        const float fx = floorf(px), fy = floorf(py);
        const int x0 = (int)fx, y0 = (int)fy;
        const float wx1 = px - fx, wy1 = py - fy;
        const float wx0 = 1.f - wx1, wy0 = 1.f - wy1;
        const float w00 = wx0 * wy0 * aw, w10 = wx1 * wy0 * aw;
        const float w01 = wx0 * wy1 * aw, w11 = wx1 * wy1 * aw;
        const bool x0v = (unsigned)x0 < (unsigned)Wl;
        const bool x1v = (unsigned)(x0 + 1) < (unsigned)Wl;
        const bool y0v = (unsigned)y0 < (unsigned)Wl;
        const bool y1v = (unsigned)(y0 + 1) < (unsigned)Wl;

        const unsigned short* base = vb + (size_t)start * CDIM;
        if (y0v) {
            const unsigned short* r0p = base + (size_t)(y0 * Wl) * CDIM;
            if (x0v) {
                const u16x4 u = *(const u16x4*)(r0p + (size_t)x0 * CDIM);
                a0 = fmaf(w00, bf2f(u[0]), a0); a1 = fmaf(w00, bf2f(u[1]), a1);
                a2 = fmaf(w00, bf2f(u[2]), a2); a3 = fmaf(w00, bf2f(u[3]), a3);
            }
            if (x1v) {
                const u16x4 u = *(const u16x4*)(r0p + (size_t)(x0 + 1) * CDIM);
                a0 = fmaf(w10, bf2f(u[0]), a0); a1 = fmaf(w10, bf2f(u[1]), a1);
                a2 = fmaf(w10, bf2f(u[2]), a2); a3 = fmaf(w10, bf2f(u[3]), a3);
            }
        }
        if (y1v) {
            const unsigned short* r1p = base + (size_t)((y0 + 1) * Wl) * CDIM;
            if (x0v) {
                const u16x4 u = *(const u16x4*)(r1p + (size_t)x0 * CDIM);
                a0 = fmaf(w01, bf2f(u[0]), a0); a1 = fmaf(w01, bf2f(u[1]), a1);
                a2 = fmaf(w01, bf2f(u[2]), a2); a3 = fmaf(w01, bf2f(u[3]), a3);
            }
            if (x1v) {
                const u16x4 u = *(const u16x4*)(r1p + (size_t)(x0 + 1) * CDIM);
                a0 = fmaf(w11, bf2f(u[0]), a0); a1 = fmaf(w11, bf2f(u[1]), a1);
                a2 = fmaf(w11, bf2f(u[2]), a2); a3 = fmaf(w11, bf2f(u[3]), a3);
            }
        }
    }

    a0 += __shfl_xor(a0, 8);  a1 += __shfl_xor(a1, 8);
    a2 += __shfl_xor(a2, 8);  a3 += __shfl_xor(a3, 8);
    a0 += __shfl_xor(a0, 16); a1 += __shfl_xor(a1, 16);
    a2 += __shfl_xor(a2, 16); a3 += __shfl_xor(a3, 16);

    if (pg == 0) {
        u16x4 o;
        o[0] = f2bf(a0); o[1] = f2bf(a1); o[2] = f2bf(a2); o[3] = f2bf(a3);
        *(u16x4*)&mid[bq * CDIM + h * HD + d4 * 4] = o;
    }
}

// ---------------------------------------------------------------------------
// Kernel C: out = mid(bf16) @ Wout + bout -> f32, swapped roles, float4 stores.
// ---------------------------------------------------------------------------
__global__ __launch_bounds__(256) void out_gemm_mfma(
    const unsigned short* __restrict__ mid, const unsigned short* __restrict__ WoutT,
    const float* __restrict__ bout, float* __restrict__ out)
{
    __shared__ unsigned short lds_w[2][256 * APAD];
    __shared__ unsigned short lds_x[2][BM * BPAD];

    const int tid = threadIdx.x;
    const int lane = tid & 63;
    const int wave = tid >> 6;
    const int wn = wave & 1;
    const int wm = wave >> 1;
    const long row0 = (long)blockIdx.x * BM;

    const unsigned short* wptr = WoutT + (size_t)tid * CDIM;
    const int xr = tid >> 1;
    const int xk = (tid & 1) * 16;
    const unsigned short* xptr = mid + (row0 + xr) * CDIM + xk;

    u16x8 wrg[4];
    u16x8 xrg[2];

    auto load_tile = [&](int kb) {
        const u16x8* qw = (const u16x8*)(wptr + kb);
        wrg[0] = qw[0]; wrg[1] = qw[1]; wrg[2] = qw[2]; wrg[3] = qw[3];
        const u16x8* qx = (const u16x8*)(xptr + kb);
        xrg[0] = qx[0]; xrg[1] = qx[1];
    };
    auto write_tile = [&](int buf) {
        u16x8* ww = (u16x8*)&lds_w[buf][tid * APAD];
        ww[0] = wrg[0]; ww[1] = wrg[1]; ww[2] = wrg[2]; ww[3] = wrg[3];
        u16x8* wx = (u16x8*)&lds_x[buf][xr * BPAD + xk];
        wx[0] = xrg[0]; wx[1] = xrg[1];
    };

    f32x4 acc[8][4] = {};
    const int la = lane & 15;
    const int lg = lane >> 4;

    load_tile(0);
    write_tile(0);
    __syncthreads();
    int cur = 0;

    for (int t = 0; t < CDIM / BK; ++t) {
        if (t + 1 < CDIM / BK) load_tile((t + 1) * BK);

        const unsigned short* pw = &lds_w[cur][(wn * 128 + la) * APAD + lg * 8];
        const unsigned short* px = &lds_x[cur][(wm * 64 + la) * BPAD + lg * 8];
        short8 xf[4];
#pragma unroll
        for (int mf = 0; mf < 4; ++mf)
            xf[mf] = *(const short8*)(px + mf * 16 * BPAD);
#pragma unroll
        for (int nf = 0; nf < 8; ++nf) {
            const short8 wf = *(const short8*)(pw + nf * 16 * APAD);
#pragma unroll
            for (int mf = 0; mf < 4; ++mf)
                acc[nf][mf] = __builtin_amdgcn_mfma_f32_16x16x32_bf16(wf, xf[mf], acc[nf][mf], 0, 0, 0);
        }

        if (t + 1 < CDIM / BK) write_tile(cur ^ 1);
        __syncthreads();
        cur ^= 1;
    }

#pragma unroll
    for (int nf = 0; nf < 8; ++nf) {
        const int nbase = wn * 128 + nf * 16 + lg * 4;
        const f32x4 bb = *(const f32x4*)&bout[nbase];
#pragma unroll
        for (int mf = 0; mf < 4; ++mf) {
            const long m = row0 + wm * 64 + mf * 16 + la;
            f32x4 o;
#pragma unroll
            for (int j = 0; j < 4; ++j) o[j] = acc[nf][mf][j] + bb[j];
            *(f32x4*)&out[m * CDIM + nbase] = o;
        }
    }
}

extern "C" void kernel_launch(void* const* d_in, const int* in_sizes, int n_in,
                              void* d_out, int out_size, void* d_ws, size_t ws_size,
                              hipStream_t stream) {
    const float* query = (const float*)d_in[0];
    const float* refp  = (const float*)d_in[1];
    const float* value = (const float*)d_in[2];
    const float* Wv    = (const float*)d_in[3];
    const float* bv    = (const float*)d_in[4];
    const float* Woff  = (const float*)d_in[5];
    const float* boff  = (const float*)d_in[6];
    const float* Watt  = (const float*)d_in[7];
    const float* batt  = (const float*)d_in[8];
    const float* Wout  = (const float*)d_in[9];
    const float* bout  = (const float*)d_in[10];
    float* out = (float*)d_out;

    char* ws = (char*)d_ws;
    unsigned short* v = (unsigned short*)ws;                        // bf16 [BS*LV][256]
    size_t off = (size_t)BS * LV * CDIM * 2;                        // 137,625,600
    float* offatt = (float*)(ws + off);                             // f32 [9600][288]
    off += (size_t)BS * LQ * NOA * 4;                               // +11,059,200
    unsigned short* mid = (unsigned short*)(ws + off);              // bf16 [9600][256]
    off += (size_t)BS * LQ * CDIM * 2;                              // +4,915,200
    unsigned short* WvT = (unsigned short*)(ws + off);
    off += 256 * 256 * 2;
    unsigned short* WoaT = (unsigned short*)(ws + off);
    off += NOA * 256 * 2;
    unsigned short* WoutT = (unsigned short*)(ws + off);

    hipFuncSetAttribute((const void*)proj_value_mfma,
                        hipFuncAttributeMaxDynamicSharedMemorySize, PROJ_LDS);

    prep_weights_kernel<<<800, 256, 0, stream>>>(Wv, Wout, Woff, Watt, WvT, WoutT, WoaT);
    proj_value_mfma<<<(BS * LV) / BM * 2, 256, PROJ_LDS, stream>>>(value, WvT, bv, v);
    offatt_gemm_mfma<<<(BS * LQ) / BM, 256, 0, stream>>>(query, WoaT, boff, batt, offatt);
    sample_kernel<<<BS * LQ, 256, 0, stream>>>(offatt, refp, v, mid);
    out_gemm_mfma<<<(BS * LQ) / BM, 256, 0, stream>>>(mid, WoutT, bout, out);
}